// Round 1
// baseline (499.456 us; speedup 1.0000x reference)
//
#include <hip/hip_runtime.h>
#include <hip/hip_bf16.h>
#include <math.h>

// MambaBlock3D: B=1, C=128, L=24^3=13824, D_INNER=256, D_STATE=16, D_CONV=4, DT_RANK=8
// All intermediates kept in channel-major (ch, L) layout.

constexpr int LQ   = 13824;   // sequence length
constexpr int NC   = 108;     // scan chunks
constexpr int CH   = 128;     // chunk length (NC*CH == L)
constexpr int DI   = 256;     // D_INNER
constexpr int DS   = 16;      // D_STATE

// ---------------- LayerNorm: x (C,L) -> tn (C,L), stats over C per l ----------------
__global__ __launch_bounds__(256) void ln_kernel(const float* __restrict__ x,
    const float* __restrict__ lnw, const float* __restrict__ lnb,
    float* __restrict__ tn, int L) {
  int l = blockIdx.x * 256 + threadIdx.x;
  float sum = 0.f, sq = 0.f;
  #pragma unroll 8
  for (int c = 0; c < 128; ++c) { float v = x[c * L + l]; sum += v; sq += v * v; }
  float mu  = sum * (1.f / 128.f);
  float var = sq * (1.f / 128.f) - mu * mu;
  float rs  = rsqrtf(var + 1e-5f);
  #pragma unroll 8
  for (int c = 0; c < 128; ++c) {
    float v = x[c * L + l];
    tn[c * L + l] = (v - mu) * rs * lnw[c] + lnb[c];
  }
}

// ---------------- Tiled fp32 GEMM: C(M,L) = W(M,K) @ B(K,L) [+ R] ----------------
// 64x64 tile, 256 threads, 4x4 microtile, float4 LDS reads.
template<int M, int K, bool RESID, bool MGUARD>
__global__ __launch_bounds__(256) void gemm64(
    const float* __restrict__ W, const float* __restrict__ Bg,
    const float* __restrict__ Rg, float* __restrict__ Cg, int L) {
  __shared__ float Wt[64][68];  // [k][e], padded stride keeps 16B alignment
  __shared__ float Bs[64][68];  // [k][l]
  const int tid = threadIdx.x;
  const int cx = tid & 15;      // l-group (4 l's each)
  const int cy = tid >> 4;      // e-group (4 e's each)
  const int l0 = blockIdx.x * 64;
  const int e0 = blockIdx.y * 64;
  float acc[4][4] = {{0.f, 0.f, 0.f, 0.f}, {0.f, 0.f, 0.f, 0.f},
                     {0.f, 0.f, 0.f, 0.f}, {0.f, 0.f, 0.f, 0.f}};
  for (int k0 = 0; k0 < K; k0 += 64) {
    #pragma unroll
    for (int i = 0; i < 16; ++i) {
      int idx = tid + i * 256;
      int e = idx >> 6, k = idx & 63;      // wave-coalesced along k
      float v = 0.f;
      if (!MGUARD || (e0 + e) < M) v = W[(size_t)(e0 + e) * K + k0 + k];
      Wt[k][e] = v;
      Bs[e][k] = Bg[(size_t)(k0 + e) * L + l0 + k];  // here e plays role of k-row, k of l
    }
    __syncthreads();
    #pragma unroll 16
    for (int k = 0; k < 64; ++k) {
      float4 wv = *(const float4*)&Wt[k][cy * 4];
      float4 bv = *(const float4*)&Bs[k][cx * 4];
      acc[0][0] += wv.x * bv.x; acc[0][1] += wv.x * bv.y; acc[0][2] += wv.x * bv.z; acc[0][3] += wv.x * bv.w;
      acc[1][0] += wv.y * bv.x; acc[1][1] += wv.y * bv.y; acc[1][2] += wv.y * bv.z; acc[1][3] += wv.y * bv.w;
      acc[2][0] += wv.z * bv.x; acc[2][1] += wv.z * bv.y; acc[2][2] += wv.z * bv.z; acc[2][3] += wv.z * bv.w;
      acc[3][0] += wv.w * bv.x; acc[3][1] += wv.w * bv.y; acc[3][2] += wv.w * bv.z; acc[3][3] += wv.w * bv.w;
    }
    __syncthreads();
  }
  #pragma unroll
  for (int i = 0; i < 4; ++i) {
    int e = e0 + cy * 4 + i;
    if (MGUARD && e >= M) continue;
    size_t off = (size_t)e * L + l0 + cx * 4;
    float4 o = make_float4(acc[i][0], acc[i][1], acc[i][2], acc[i][3]);
    if (RESID) {
      float4 r = *(const float4*)&Rg[off];
      o.x += r.x; o.y += r.y; o.z += r.z; o.w += r.w;
    }
    *(float4*)&Cg[off] = o;
  }
}

// ---------------- Causal depthwise conv (k=4) + SiLU: xs (DI,L) -> xa (DI,L) ----------------
__global__ __launch_bounds__(256) void conv_silu(const float* __restrict__ xs,
    const float* __restrict__ cw, const float* __restrict__ cb,
    float* __restrict__ xa, int L) {
  int idx = blockIdx.x * 256 + threadIdx.x;    // idx = d*L + l
  int d = idx / LQ;
  int l = idx - d * LQ;
  float acc = cb[d];
  #pragma unroll
  for (int k = 0; k < 4; ++k) {
    int ls = l + k - 3;
    float v = (ls >= 0) ? xs[d * L + ls] : 0.f;
    acc += v * cw[d * 4 + k];
  }
  xa[idx] = acc / (1.f + __expf(-acc));        // silu
}

// ---------------- dt projection (K=8) + softplus ----------------
__global__ __launch_bounds__(256) void dtproj(const float* __restrict__ Wdt,
    const float* __restrict__ bias, const float* __restrict__ xdbl,
    float* __restrict__ dt, int L) {
  int idx = blockIdx.x * 256 + threadIdx.x;    // d*L + l
  int d = idx / LQ;
  int l = idx - d * LQ;
  float acc = bias[d];
  #pragma unroll
  for (int r = 0; r < 8; ++r) acc += Wdt[d * 8 + r] * xdbl[(size_t)r * L + l];
  dt[idx] = (acc > 20.f) ? acc : log1pf(__expf(acc));
}

// ---------------- Scan pass 1: per-chunk (P, H) ----------------
// thread = (chunk c via blockIdx.x, d via blockIdx.y*16 + tid>>4, s via tid&15)
__global__ __launch_bounds__(256) void scan_pass1(const float* __restrict__ dt,
    const float* __restrict__ xa, const float* __restrict__ xdbl,
    const float* __restrict__ A_log, float* __restrict__ Pc, float* __restrict__ Hc, int L) {
  int s = threadIdx.x & 15;
  int d = blockIdx.y * 16 + (threadIdx.x >> 4);
  int c = blockIdx.x;
  float A = -__expf(A_log[d * DS + s]);
  const float* __restrict__ Brow = xdbl + (size_t)(8 + s) * L;
  int l0 = c * CH;
  float p = 1.f, h = 0.f;
  for (int i = 0; i < CH; ++i) {
    int l = l0 + i;
    float dtv = dt[(size_t)d * L + l];
    float xav = xa[(size_t)d * L + l];
    float a = __expf(dtv * A);
    p *= a;
    h = a * h + dtv * xav * Brow[l];
  }
  int idx = (c * DI + d) * DS + s;   // [NC][DI][DS]
  Pc[idx] = p; Hc[idx] = h;
}

// ---------------- Scan combine: serial over chunks (only NC steps) ----------------
__global__ __launch_bounds__(256) void scan_combine(const float* __restrict__ Pc,
    const float* __restrict__ Hc, float* __restrict__ Hin) {
  int t = blockIdx.x * 256 + threadIdx.x;  // 0..4095 = d*16+s
  float h = 0.f;
  for (int c = 0; c < NC; ++c) {
    Hin[c * 4096 + t] = h;
    h = Pc[c * 4096 + t] * h + Hc[c * 4096 + t];
  }
}

// ---------------- Scan pass 2: replay with correct h_in, produce gated y ----------------
__global__ __launch_bounds__(256) void scan_pass2(const float* __restrict__ dt,
    const float* __restrict__ xa, const float* __restrict__ xdbl,
    const float* __restrict__ zt, const float* __restrict__ A_log,
    const float* __restrict__ Dp, const float* __restrict__ Hin,
    float* __restrict__ yg, int L) {
  int s = threadIdx.x & 15;
  int d = blockIdx.y * 16 + (threadIdx.x >> 4);
  int c = blockIdx.x;
  float A = -__expf(A_log[d * DS + s]);
  const float* __restrict__ Brow = xdbl + (size_t)(8 + s) * L;
  const float* __restrict__ Crow = xdbl + (size_t)(24 + s) * L;
  float h = Hin[c * 4096 + d * DS + s];
  float Dv = Dp[d];
  int l0 = c * CH;
  for (int i = 0; i < CH; ++i) {
    int l = l0 + i;
    float dtv = dt[(size_t)d * L + l];
    float xav = xa[(size_t)d * L + l];
    float a = __expf(dtv * A);
    h = a * h + dtv * xav * Brow[l];
    float t = h * Crow[l];
    // reduce over the 16 state lanes (s occupies lane bits 0..3)
    t += __shfl_xor(t, 1);
    t += __shfl_xor(t, 2);
    t += __shfl_xor(t, 4);
    t += __shfl_xor(t, 8);
    if (s == 0) {
      float zv = zt[(size_t)d * L + l];
      float sig = 1.f / (1.f + __expf(-zv));
      yg[(size_t)d * L + l] = (t + xav * Dv) * (zv * sig);
    }
  }
}

extern "C" void kernel_launch(void* const* d_in, const int* in_sizes, int n_in,
                              void* d_out, int out_size, void* d_ws, size_t ws_size,
                              hipStream_t stream) {
  const float* x         = (const float*)d_in[0];
  const float* ln_w      = (const float*)d_in[1];
  const float* ln_b      = (const float*)d_in[2];
  const float* in_proj_w = (const float*)d_in[3];
  const float* conv_w    = (const float*)d_in[4];
  const float* conv_b    = (const float*)d_in[5];
  const float* x_proj_w  = (const float*)d_in[6];
  const float* dt_proj_w = (const float*)d_in[7];
  const float* dt_proj_b = (const float*)d_in[8];
  const float* A_log     = (const float*)d_in[9];
  const float* D_param   = (const float*)d_in[10];
  const float* out_proj_w= (const float*)d_in[11];
  float* out = (float*)d_out;

  const int L = LQ;
  float* ws = (float*)d_ws;
  // layout (floats), with lifetime-based reuse:
  //  [0,128L)      tn   (dead after gemm_in)  -> reused for xdbl [0,40L)
  //  [128L,640L)   xz   (xs rows 0..255 dead after conv -> reused for yg [128L,384L);
  //                 z rows at [384L,640L) live until scan_pass2)
  //  [640L,896L)   xa
  //  [896L,1152L)  dt
  //  [1152L,1184L) Pc   [1184L,1216L) Hc   [1216L,1248L) Hin
  float* tn   = ws;
  float* xz   = ws + (size_t)128 * L;
  float* xs   = xz;                           // rows 0..255
  float* zt   = xz + (size_t)DI * L;          // rows 256..511
  float* xa   = ws + (size_t)640 * L;
  float* xdbl = ws;                           // reuse tn region (40 rows)
  float* dt   = ws + (size_t)896 * L;
  float* yg   = ws + (size_t)128 * L;         // reuse xs region
  float* Pc   = ws + (size_t)1152 * L;
  float* Hc   = ws + (size_t)1184 * L;
  float* Hin  = ws + (size_t)1216 * L;

  ln_kernel<<<L / 256, 256, 0, stream>>>(x, ln_w, ln_b, tn, L);
  gemm64<512, 128, false, false><<<dim3(L / 64, 8), 256, 0, stream>>>(in_proj_w, tn, nullptr, xz, L);
  conv_silu<<<(DI * L) / 256, 256, 0, stream>>>(xs, conv_w, conv_b, xa, L);
  gemm64<40, 256, false, true><<<dim3(L / 64, 1), 256, 0, stream>>>(x_proj_w, xa, nullptr, xdbl, L);
  dtproj<<<(DI * L) / 256, 256, 0, stream>>>(dt_proj_w, dt_proj_b, xdbl, dt, L);
  scan_pass1<<<dim3(NC, 16), 256, 0, stream>>>(dt, xa, xdbl, A_log, Pc, Hc, L);
  scan_combine<<<16, 256, 0, stream>>>(Pc, Hc, Hin);
  scan_pass2<<<dim3(NC, 16), 256, 0, stream>>>(dt, xa, xdbl, zt, A_log, D_param, Hin, yg, L);
  gemm64<128, 256, true, false><<<dim3(L / 64, 2), 256, 0, stream>>>(out_proj_w, yg, x, out, L);
}

// Round 2
// 286.688 us; speedup vs baseline: 1.7422x; 1.7422x over previous
//
#include <hip/hip_runtime.h>
#include <hip/hip_bf16.h>
#include <math.h>

// MambaBlock3D: B=1, C=128, L=24^3=13824, D_INNER=256, D_STATE=16, D_CONV=4, DT_RANK=8
// All intermediates kept in channel-major (ch, L) layout.

constexpr int LQ   = 13824;   // sequence length
constexpr int NC   = 108;     // scan chunks
constexpr int CH   = 128;     // chunk length (NC*CH == L)
constexpr int DI   = 256;     // D_INNER
constexpr int DS   = 16;      // D_STATE

// DPP-based add from a permuted lane (pure VALU, no DS pipe).
template<int CTRL>
__device__ __forceinline__ float dpp_add(float x) {
  int y = __builtin_amdgcn_update_dpp(0, __float_as_int(x), CTRL, 0xF, 0xF, true);
  return x + __int_as_float(y);
}

// ---------------- LayerNorm: x (C,L) -> tn (C,L), stats over C per l ----------------
__global__ __launch_bounds__(256) void ln_kernel(const float* __restrict__ x,
    const float* __restrict__ lnw, const float* __restrict__ lnb,
    float* __restrict__ tn, int L) {
  int l = blockIdx.x * 256 + threadIdx.x;
  float sum = 0.f, sq = 0.f;
  #pragma unroll 8
  for (int c = 0; c < 128; ++c) { float v = x[c * L + l]; sum += v; sq += v * v; }
  float mu  = sum * (1.f / 128.f);
  float var = sq * (1.f / 128.f) - mu * mu;
  float rs  = rsqrtf(var + 1e-5f);
  #pragma unroll 8
  for (int c = 0; c < 128; ++c) {
    float v = x[c * L + l];
    tn[c * L + l] = (v - mu) * rs * lnw[c] + lnb[c];
  }
}

// ---------------- Tiled fp32 GEMM: C(M,L) = W(M,K) @ B(K,L) [+ R] ----------------
template<int M, int K, bool RESID, bool MGUARD>
__global__ __launch_bounds__(256) void gemm64(
    const float* __restrict__ W, const float* __restrict__ Bg,
    const float* __restrict__ Rg, float* __restrict__ Cg, int L) {
  __shared__ float Wt[64][68];
  __shared__ float Bs[64][68];
  const int tid = threadIdx.x;
  const int cx = tid & 15;
  const int cy = tid >> 4;
  const int l0 = blockIdx.x * 64;
  const int e0 = blockIdx.y * 64;
  float acc[4][4] = {{0.f, 0.f, 0.f, 0.f}, {0.f, 0.f, 0.f, 0.f},
                     {0.f, 0.f, 0.f, 0.f}, {0.f, 0.f, 0.f, 0.f}};
  for (int k0 = 0; k0 < K; k0 += 64) {
    #pragma unroll
    for (int i = 0; i < 16; ++i) {
      int idx = tid + i * 256;
      int e = idx >> 6, k = idx & 63;
      float v = 0.f;
      if (!MGUARD || (e0 + e) < M) v = W[(size_t)(e0 + e) * K + k0 + k];
      Wt[k][e] = v;
      Bs[e][k] = Bg[(size_t)(k0 + e) * L + l0 + k];
    }
    __syncthreads();
    #pragma unroll 16
    for (int k = 0; k < 64; ++k) {
      float4 wv = *(const float4*)&Wt[k][cy * 4];
      float4 bv = *(const float4*)&Bs[k][cx * 4];
      acc[0][0] += wv.x * bv.x; acc[0][1] += wv.x * bv.y; acc[0][2] += wv.x * bv.z; acc[0][3] += wv.x * bv.w;
      acc[1][0] += wv.y * bv.x; acc[1][1] += wv.y * bv.y; acc[1][2] += wv.y * bv.z; acc[1][3] += wv.y * bv.w;
      acc[2][0] += wv.z * bv.x; acc[2][1] += wv.z * bv.y; acc[2][2] += wv.z * bv.z; acc[2][3] += wv.z * bv.w;
      acc[3][0] += wv.w * bv.x; acc[3][1] += wv.w * bv.y; acc[3][2] += wv.w * bv.z; acc[3][3] += wv.w * bv.w;
    }
    __syncthreads();
  }
  #pragma unroll
  for (int i = 0; i < 4; ++i) {
    int e = e0 + cy * 4 + i;
    if (MGUARD && e >= M) continue;
    size_t off = (size_t)e * L + l0 + cx * 4;
    float4 o = make_float4(acc[i][0], acc[i][1], acc[i][2], acc[i][3]);
    if (RESID) {
      float4 r = *(const float4*)&Rg[off];
      o.x += r.x; o.y += r.y; o.z += r.z; o.w += r.w;
    }
    *(float4*)&Cg[off] = o;
  }
}

// ---------------- Causal depthwise conv (k=4) + SiLU ----------------
__global__ __launch_bounds__(256) void conv_silu(const float* __restrict__ xs,
    const float* __restrict__ cw, const float* __restrict__ cb,
    float* __restrict__ xa, int L) {
  int idx = blockIdx.x * 256 + threadIdx.x;
  int d = idx / LQ;
  int l = idx - d * LQ;
  float acc = cb[d];
  #pragma unroll
  for (int k = 0; k < 4; ++k) {
    int ls = l + k - 3;
    float v = (ls >= 0) ? xs[d * L + ls] : 0.f;
    acc += v * cw[d * 4 + k];
  }
  xa[idx] = acc / (1.f + __expf(-acc));
}

// ---------------- dt projection (K=8) + softplus ----------------
__global__ __launch_bounds__(256) void dtproj(const float* __restrict__ Wdt,
    const float* __restrict__ bias, const float* __restrict__ xdbl,
    float* __restrict__ dt, int L) {
  int idx = blockIdx.x * 256 + threadIdx.x;
  int d = idx / LQ;
  int l = idx - d * LQ;
  float acc = bias[d];
  #pragma unroll
  for (int r = 0; r < 8; ++r) acc += Wdt[d * 8 + r] * xdbl[(size_t)r * L + l];
  dt[idx] = (acc > 20.f) ? acc : log1pf(__expf(acc));
}

// ---------------- Scan pass 1: per-chunk (P, H), LDS-staged ----------------
// Block = (chunk c, 16-d group). LDS: du[(dt, dt*xa)] rows stride 260 fl,
// Bs rows stride 132 fl. Inner loop: 1 ds_read_b64 + 1 ds_read_b32.
__global__ __launch_bounds__(256) void scan_pass1(const float* __restrict__ dtg,
    const float* __restrict__ xag, const float* __restrict__ xdbl,
    const float* __restrict__ A_log, float* __restrict__ Pc, float* __restrict__ Hc) {
  __shared__ float du[16 * 260];
  __shared__ float Bsh[16 * 132];
  const int tid = threadIdx.x;
  const int c = blockIdx.x, dg = blockIdx.y;
  const int l0 = c * CH;
  #pragma unroll
  for (int a = 0; a < 2; ++a) {
    int idx = a * 256 + tid;
    int row = idx >> 5, col = idx & 31;
    size_t g = (size_t)(dg * 16 + row) * LQ + l0 + col * 4;
    float4 d4 = *(const float4*)&dtg[g];
    float4 x4 = *(const float4*)&xag[g];
    *(float4*)&du[row * 260 + col * 8]     = make_float4(d4.x, d4.x * x4.x, d4.y, d4.y * x4.y);
    *(float4*)&du[row * 260 + col * 8 + 4] = make_float4(d4.z, d4.z * x4.z, d4.w, d4.w * x4.w);
    float4 b4 = *(const float4*)&xdbl[(size_t)(8 + row) * LQ + l0 + col * 4];
    *(float4*)&Bsh[row * 132 + col * 4] = b4;
  }
  __syncthreads();
  const int s = tid & 15, dloc = tid >> 4;
  const float A = -__expf(A_log[(dg * 16 + dloc) * DS + s]);
  const float2* __restrict__ durow = (const float2*)&du[dloc * 260];
  const float*  __restrict__ brow  = &Bsh[s * 132];
  float p = 1.f, h = 0.f;
  #pragma unroll 4
  for (int i = 0; i < CH; ++i) {
    float2 v = durow[i];
    float a_ = __expf(v.x * A);
    p *= a_;
    h = fmaf(a_, h, v.y * brow[i]);
  }
  int idx = (c * DI + dg * 16 + dloc) * DS + s;
  Pc[idx] = p; Hc[idx] = h;
}

// ---------------- Scan combine: serial over chunks ----------------
__global__ __launch_bounds__(256) void scan_combine(const float* __restrict__ Pc,
    const float* __restrict__ Hc, float* __restrict__ Hin) {
  int t = blockIdx.x * 256 + threadIdx.x;
  float h = 0.f;
  for (int c = 0; c < NC; ++c) {
    Hin[c * 4096 + t] = h;
    h = Pc[c * 4096 + t] * h + Hc[c * 4096 + t];
  }
}

// ---------------- Scan pass 2: replay + DPP reduce + gated coalesced epilogue ----------------
__global__ __launch_bounds__(256) void scan_pass2(const float* __restrict__ dtg,
    const float* __restrict__ xag, const float* __restrict__ xdbl,
    const float* __restrict__ zt, const float* __restrict__ A_log,
    const float* __restrict__ Dp, const float* __restrict__ Hin,
    float* __restrict__ yg) {
  __shared__ float du[16 * 260];   // (dt, dt*xa) interleaved
  __shared__ float bc[16 * 260];   // (B, C) interleaved
  __shared__ float ylds[16 * 132];
  const int tid = threadIdx.x;
  const int c = blockIdx.x, dg = blockIdx.y;
  const int l0 = c * CH;
  #pragma unroll
  for (int a = 0; a < 2; ++a) {
    int idx = a * 256 + tid;
    int row = idx >> 5, col = idx & 31;
    size_t g = (size_t)(dg * 16 + row) * LQ + l0 + col * 4;
    float4 d4 = *(const float4*)&dtg[g];
    float4 x4 = *(const float4*)&xag[g];
    *(float4*)&du[row * 260 + col * 8]     = make_float4(d4.x, d4.x * x4.x, d4.y, d4.y * x4.y);
    *(float4*)&du[row * 260 + col * 8 + 4] = make_float4(d4.z, d4.z * x4.z, d4.w, d4.w * x4.w);
    size_t gb = (size_t)(8 + row) * LQ + l0 + col * 4;
    float4 b4 = *(const float4*)&xdbl[gb];
    float4 c4 = *(const float4*)&xdbl[gb + (size_t)16 * LQ];
    *(float4*)&bc[row * 260 + col * 8]     = make_float4(b4.x, c4.x, b4.y, c4.y);
    *(float4*)&bc[row * 260 + col * 8 + 4] = make_float4(b4.z, c4.z, b4.w, c4.w);
  }
  __syncthreads();
  const int s = tid & 15, dloc = tid >> 4;
  const int d = dg * 16 + dloc;
  const float A = -__expf(A_log[d * DS + s]);
  float h = Hin[c * 4096 + d * 16 + s];
  const float2* __restrict__ durow = (const float2*)&du[dloc * 260];
  const float2* __restrict__ bcrow = (const float2*)&bc[s * 260];
  float* __restrict__ yrow = &ylds[dloc * 132];
  #pragma unroll 4
  for (int i = 0; i < CH; ++i) {
    float2 v = durow[i];
    float2 w = bcrow[i];
    float a_ = __expf(v.x * A);
    h = fmaf(a_, h, v.y * w.x);
    float t = h * w.y;
    // sum over the 16 state lanes, pure-VALU DPP tree
    t = dpp_add<0xB1>(t);    // quad_perm [1,0,3,2]  (xor 1)
    t = dpp_add<0x4E>(t);    // quad_perm [2,3,0,1]  (xor 2)
    t = dpp_add<0x141>(t);   // row_half_mirror      (completes 8-group)
    t = dpp_add<0x140>(t);   // row_mirror           (completes 16-group)
    if (s == 0) yrow[i] = t;
  }
  __syncthreads();
  // epilogue: yg = (t + xa*D) * silu(z), coalesced float4
  #pragma unroll
  for (int a = 0; a < 2; ++a) {
    int idx = a * 256 + tid;
    int row = idx >> 5, col = idx & 31;
    int dd = dg * 16 + row;
    size_t g = (size_t)dd * LQ + l0 + col * 4;
    float4 ts = *(const float4*)&ylds[row * 132 + col * 4];
    float4 xv = *(const float4*)&xag[g];
    float4 zv = *(const float4*)&zt[g];
    float Dv = Dp[dd];
    float4 o;
    o.x = (ts.x + xv.x * Dv) * (zv.x / (1.f + __expf(-zv.x)));
    o.y = (ts.y + xv.y * Dv) * (zv.y / (1.f + __expf(-zv.y)));
    o.z = (ts.z + xv.z * Dv) * (zv.z / (1.f + __expf(-zv.z)));
    o.w = (ts.w + xv.w * Dv) * (zv.w / (1.f + __expf(-zv.w)));
    *(float4*)&yg[g] = o;
  }
}

extern "C" void kernel_launch(void* const* d_in, const int* in_sizes, int n_in,
                              void* d_out, int out_size, void* d_ws, size_t ws_size,
                              hipStream_t stream) {
  const float* x         = (const float*)d_in[0];
  const float* ln_w      = (const float*)d_in[1];
  const float* ln_b      = (const float*)d_in[2];
  const float* in_proj_w = (const float*)d_in[3];
  const float* conv_w    = (const float*)d_in[4];
  const float* conv_b    = (const float*)d_in[5];
  const float* x_proj_w  = (const float*)d_in[6];
  const float* dt_proj_w = (const float*)d_in[7];
  const float* dt_proj_b = (const float*)d_in[8];
  const float* A_log     = (const float*)d_in[9];
  const float* D_param   = (const float*)d_in[10];
  const float* out_proj_w= (const float*)d_in[11];
  float* out = (float*)d_out;

  const int L = LQ;
  float* ws = (float*)d_ws;
  float* tn   = ws;
  float* xz   = ws + (size_t)128 * L;
  float* xs   = xz;                           // rows 0..255
  float* zt   = xz + (size_t)DI * L;          // rows 256..511
  float* xa   = ws + (size_t)640 * L;
  float* xdbl = ws;                           // reuse tn region (40 rows)
  float* dt   = ws + (size_t)896 * L;
  float* yg   = ws + (size_t)128 * L;         // reuse xs region
  float* Pc   = ws + (size_t)1152 * L;
  float* Hc   = ws + (size_t)1184 * L;
  float* Hin  = ws + (size_t)1216 * L;

  ln_kernel<<<L / 256, 256, 0, stream>>>(x, ln_w, ln_b, tn, L);
  gemm64<512, 128, false, false><<<dim3(L / 64, 8), 256, 0, stream>>>(in_proj_w, tn, nullptr, xz, L);
  conv_silu<<<(DI * L) / 256, 256, 0, stream>>>(xs, conv_w, conv_b, xa, L);
  gemm64<40, 256, false, true><<<dim3(L / 64, 1), 256, 0, stream>>>(x_proj_w, xa, nullptr, xdbl, L);
  dtproj<<<(DI * L) / 256, 256, 0, stream>>>(dt_proj_w, dt_proj_b, xdbl, dt, L);
  scan_pass1<<<dim3(NC, 16), 256, 0, stream>>>(dt, xa, xdbl, A_log, Pc, Hc);
  scan_combine<<<16, 256, 0, stream>>>(Pc, Hc, Hin);
  scan_pass2<<<dim3(NC, 16), 256, 0, stream>>>(dt, xa, xdbl, zt, A_log, D_param, Hin, yg);
  gemm64<128, 256, true, false><<<dim3(L / 64, 2), 256, 0, stream>>>(out_proj_w, yg, x, out, L);
}

// Round 4
// 203.838 us; speedup vs baseline: 2.4503x; 1.4064x over previous
//
#include <hip/hip_runtime.h>
#include <hip/hip_bf16.h>
#include <math.h>

// MambaBlock3D: B=1, C=128, L=24^3=13824, D_INNER=256, D_STATE=16, D_CONV=4, DT_RANK=8
// Token-major bf16 activations, MFMA GEMMs, fp32 scan.

constexpr int LQ = 13824;
constexpr int NC = 108;
constexpr int CH = 128;
constexpr int DI = 256;
constexpr int DS = 16;

typedef __attribute__((ext_vector_type(8))) short short8v;   // 8 bf16 = 4 VGPR
typedef __attribute__((ext_vector_type(4))) float float4v;

__device__ __forceinline__ ushort f2bf(float f) {
  uint u = __float_as_uint(f);
  u += 0x7FFFu + ((u >> 16) & 1u);          // round-to-nearest-even
  return (ushort)(u >> 16);
}
__device__ __forceinline__ float bf2f(ushort u) {
  return __uint_as_float(((uint)u) << 16);
}

template<int CTRL>
__device__ __forceinline__ float dpp_add(float x) {
  int y = __builtin_amdgcn_update_dpp(0, __float_as_int(x), CTRL, 0xF, 0xF, true);
  return x + __int_as_float(y);
}

// ---------------- weight prep: fp32 -> bf16 (x_proj padded to 64 rows) ----------------
__global__ __launch_bounds__(256) void prep_w(const float* __restrict__ w_in,
    const float* __restrict__ w_xp, const float* __restrict__ w_out,
    ushort* __restrict__ b_in, ushort* __restrict__ b_xp, ushort* __restrict__ b_out) {
  int idx = blockIdx.x * 256 + threadIdx.x;
  if (idx < 512 * 128) {
    b_in[idx] = f2bf(w_in[idx]);
  } else if (idx < 512 * 128 + 64 * 256) {
    int j = idx - 512 * 128; int r = j >> 8, k = j & 255;
    b_xp[j] = (r < 40) ? f2bf(w_xp[r * 256 + k]) : (ushort)0;
  } else if (idx < 512 * 128 + 64 * 256 + 128 * 256) {
    int j = idx - (512 * 128 + 64 * 256);
    b_out[j] = f2bf(w_out[j]);
  }
}

// ---------------- LayerNorm: x (C,L) fp32 -> tn (L,128) bf16 token-major ----------------
__global__ __launch_bounds__(256) void ln_t(const float* __restrict__ x,
    const float* __restrict__ lnw, const float* __restrict__ lnb,
    ushort* __restrict__ tn) {
  __shared__ float red[64][8];
  __shared__ float stat[64][2];
  __shared__ ushort T[64][136];   // [l][c] bf16, padded rows (272B, 16B-mult)
  const int t = threadIdx.x;
  const int l = t & 63, q = t >> 6;
  const int l0 = blockIdx.x * 64;
  float sum = 0.f, sq = 0.f;
  #pragma unroll 8
  for (int cc = 0; cc < 32; ++cc) {
    int c = q * 32 + cc;
    float v = x[(size_t)c * LQ + l0 + l];
    sum += v; sq += v * v;
  }
  red[l][q] = sum; red[l][4 + q] = sq;
  __syncthreads();
  if (t < 64) {
    float s  = red[t][0] + red[t][1] + red[t][2] + red[t][3];
    float s2 = red[t][4] + red[t][5] + red[t][6] + red[t][7];
    float mu = s * (1.f / 128.f);
    float var = s2 * (1.f / 128.f) - mu * mu;
    stat[t][0] = mu; stat[t][1] = rsqrtf(var + 1e-5f);
  }
  __syncthreads();
  float mu = stat[l][0], rs = stat[l][1];
  #pragma unroll 8
  for (int cc = 0; cc < 32; ++cc) {
    int c = q * 32 + cc;
    float v = x[(size_t)c * LQ + l0 + l];
    T[l][c] = f2bf((v - mu) * rs * lnw[c] + lnb[c]);
  }
  __syncthreads();
  int row = t >> 2, seg = t & 3;
  #pragma unroll
  for (int j = 0; j < 4; ++j) {
    short8v v = *(const short8v*)&T[row][seg * 32 + j * 8];
    *(short8v*)&tn[(size_t)(l0 + row) * 128 + seg * 32 + j * 8] = v;
  }
}

// ---------------- MFMA GEMM (token-major out): Out(L,CSTR)[.,m0..m0+MV) = Act(L,BSTR) @ Wb^T ----------------
// Block: 128 l x 64 m, 4 waves (each 32 l x 64 m), K-loop BK=64, XOR-swizzled LDS.
template<int K, int MV, int BSTR, int CSTR>
__global__ __launch_bounds__(256) void gemm_tok(
    const ushort* __restrict__ Wb,    // (64*gridDim.y) x K bf16 row-major
    const ushort* __restrict__ Act,   // (L, BSTR) bf16 token-major
    ushort* __restrict__ Out) {
  constexpr int KO = K / 8;
  __shared__ ushort As[64 * K];
  __shared__ ushort Bs[128 * 64];     // K-step tile; reused as epilogue [l][m] tile
  const int tid = threadIdx.x;
  const int l0 = blockIdx.x * 128;
  const int m0 = blockIdx.y * 64;
  #pragma unroll
  for (int i = 0; i < (64 * KO) / 256; ++i) {
    int cid = i * 256 + tid;
    int m = cid / KO, oct = cid % KO;
    short8v v = *(const short8v*)&Wb[(size_t)(m0 + m) * K + oct * 8];
    *(short8v*)&As[m * K + ((oct ^ (m & 7)) * 8)] = v;
  }
  float4v acc[4][2];
  #pragma unroll
  for (int a = 0; a < 4; ++a)
    #pragma unroll
    for (int b = 0; b < 2; ++b) acc[a][b] = (float4v)0.f;
  const int w = tid >> 6, lane = tid & 63;
  const int r = lane & 15, g = lane >> 4;
  for (int k0 = 0; k0 < K; k0 += 64) {
    __syncthreads();
    #pragma unroll
    for (int i = 0; i < 4; ++i) {
      int cid = i * 256 + tid;
      int l = cid >> 3, oct = cid & 7;
      short8v v = *(const short8v*)&Act[(size_t)(l0 + l) * BSTR + k0 + oct * 8];
      *(short8v*)&Bs[l * 64 + ((oct ^ (l & 7)) * 8)] = v;
    }
    __syncthreads();
    #pragma unroll
    for (int kk = 0; kk < 2; ++kk) {
      short8v af[4], bfv[2];
      int ko = (k0 >> 3) + kk * 4 + g;
      #pragma unroll
      for (int mf = 0; mf < 4; ++mf) {
        int row = mf * 16 + r;
        af[mf] = *(const short8v*)&As[row * K + ((ko ^ (row & 7)) * 8)];
      }
      int kob = kk * 4 + g;
      #pragma unroll
      for (int nf = 0; nf < 2; ++nf) {
        int row = w * 32 + nf * 16 + r;
        bfv[nf] = *(const short8v*)&Bs[row * 64 + ((kob ^ (row & 7)) * 8)];
      }
      #pragma unroll
      for (int mf = 0; mf < 4; ++mf)
        #pragma unroll
        for (int nf = 0; nf < 2; ++nf)
          acc[mf][nf] = __builtin_amdgcn_mfma_f32_16x16x32_bf16(af[mf], bfv[nf], acc[mf][nf], 0, 0, 0);
    }
  }
  __syncthreads();
  // epilogue: dump [l][m] bf16 tile into Bs (swizzled), then coalesced store
  #pragma unroll
  for (int mf = 0; mf < 4; ++mf) {
    #pragma unroll
    for (int nf = 0; nf < 2; ++nf) {
      int l = w * 32 + nf * 16 + r;
      int m = mf * 16 + g * 4;
      ushort u0 = f2bf(acc[mf][nf][0]), u1 = f2bf(acc[mf][nf][1]);
      ushort u2 = f2bf(acc[mf][nf][2]), u3 = f2bf(acc[mf][nf][3]);
      uint2 pk = make_uint2((uint)u0 | ((uint)u1 << 16), (uint)u2 | ((uint)u3 << 16));
      int oct = (m >> 3) ^ (l & 7);
      *(uint2*)&Bs[l * 64 + oct * 8 + (g & 1) * 4] = pk;
    }
  }
  __syncthreads();
  #pragma unroll
  for (int i = 0; i < 4; ++i) {
    int cid = i * 256 + tid;
    int row = cid >> 3, oct = cid & 7;
    if (oct * 8 < MV) {
      short8v v = *(const short8v*)&Bs[row * 64 + ((oct ^ (row & 7)) * 8)];
      *(short8v*)&Out[(size_t)(l0 + row) * CSTR + m0 + oct * 8] = v;
    }
  }
}

// ---------------- out_proj GEMM (swapped operands): out(C,L) = W(128,256) @ yg^T + x ----------------
// A = yg (rows l), B = W (cols c). D-frag: lane holds 4 consecutive l at fixed c -> direct float4 store.
__global__ __launch_bounds__(256) void gemm_out_k(
    const ushort* __restrict__ Wb,    // 128 x 256 bf16 [c][k]
    const ushort* __restrict__ Yg,    // 16 slabs of (L,16) bf16  [slab][l][16]
    const float* __restrict__ X,
    float* __restrict__ Out) {
  __shared__ ushort Ay[128 * 64];
  __shared__ ushort Bw[128 * 64];
  const int tid = threadIdx.x;
  const int l0 = blockIdx.x * 128;
  const int w = tid >> 6, lane = tid & 63;
  const int r = lane & 15, g = lane >> 4;
  const int lw = w >> 1, cw = w & 1;
  float4v acc[4][4];
  #pragma unroll
  for (int a = 0; a < 4; ++a)
    #pragma unroll
    for (int b = 0; b < 4; ++b) acc[a][b] = (float4v)0.f;
  for (int k0 = 0; k0 < 256; k0 += 64) {
    __syncthreads();
    #pragma unroll
    for (int i = 0; i < 4; ++i) {
      int cid = i * 256 + tid;
      int row = cid >> 3, oct = cid & 7;
      int k = k0 + oct * 8;
      int slab = k >> 4, rem = k & 15;
      short8v va = *(const short8v*)&Yg[((size_t)slab * LQ + l0 + row) * 16 + rem];
      *(short8v*)&Ay[row * 64 + ((oct ^ (row & 7)) * 8)] = va;
      short8v vb = *(const short8v*)&Wb[(size_t)row * 256 + k0 + oct * 8];
      *(short8v*)&Bw[row * 64 + ((oct ^ (row & 7)) * 8)] = vb;
    }
    __syncthreads();
    #pragma unroll
    for (int kk = 0; kk < 2; ++kk) {
      int ko = kk * 4 + g;
      short8v af[4], bfv[4];
      #pragma unroll
      for (int mf = 0; mf < 4; ++mf) {
        int row = lw * 64 + mf * 16 + r;
        af[mf] = *(const short8v*)&Ay[row * 64 + ((ko ^ (row & 7)) * 8)];
      }
      #pragma unroll
      for (int nf = 0; nf < 4; ++nf) {
        int row = cw * 64 + nf * 16 + r;
        bfv[nf] = *(const short8v*)&Bw[row * 64 + ((ko ^ (row & 7)) * 8)];
      }
      #pragma unroll
      for (int mf = 0; mf < 4; ++mf)
        #pragma unroll
        for (int nf = 0; nf < 4; ++nf)
          acc[mf][nf] = __builtin_amdgcn_mfma_f32_16x16x32_bf16(af[mf], bfv[nf], acc[mf][nf], 0, 0, 0);
    }
  }
  #pragma unroll
  for (int mf = 0; mf < 4; ++mf) {
    #pragma unroll
    for (int nf = 0; nf < 4; ++nf) {
      int c = cw * 64 + nf * 16 + r;
      int l = l0 + lw * 64 + mf * 16 + g * 4;
      size_t off = (size_t)c * LQ + l;
      float4 rv = *(const float4*)&X[off];
      float4 o = make_float4(acc[mf][nf][0] + rv.x, acc[mf][nf][1] + rv.y,
                             acc[mf][nf][2] + rv.z, acc[mf][nf][3] + rv.w);
      *(float4*)&Out[off] = o;
    }
  }
}

// ---------------- causal depthwise conv (k=4) + SiLU, token-major ----------------
__global__ __launch_bounds__(256) void conv_silu_t(const ushort* __restrict__ xz,
    const float* __restrict__ cw, const float* __restrict__ cb,
    ushort* __restrict__ xa) {
  const int l = blockIdx.x, d = threadIdx.x;
  float4 wv = *(const float4*)&cw[d * 4];
  float acc = cb[d];
  if (l >= 3) acc += bf2f(xz[(size_t)(l - 3) * 512 + d]) * wv.x;
  if (l >= 2) acc += bf2f(xz[(size_t)(l - 2) * 512 + d]) * wv.y;
  if (l >= 1) acc += bf2f(xz[(size_t)(l - 1) * 512 + d]) * wv.z;
  acc += bf2f(xz[(size_t)l * 512 + d]) * wv.w;
  xa[(size_t)l * 256 + d] = f2bf(acc / (1.f + __expf(-acc)));
}

// ---------------- dt projection (K=8) + softplus, token-major ----------------
__global__ __launch_bounds__(256) void dtproj_t(const ushort* __restrict__ xdbl,
    const float* __restrict__ Wdt, const float* __restrict__ bias,
    ushort* __restrict__ dt) {
  const int l = blockIdx.x, d = threadIdx.x;
  float acc = bias[d];
  #pragma unroll
  for (int rr = 0; rr < 8; ++rr)
    acc += Wdt[d * 8 + rr] * bf2f(xdbl[(size_t)l * 48 + rr]);
  float sp = (acc > 20.f) ? acc : log1pf(__expf(acc));
  dt[(size_t)l * 256 + d] = f2bf(sp);
}

// ---------------- scan pass 1: per-chunk (P, H) ----------------
__global__ __launch_bounds__(256) void scan_pass1_t(const ushort* __restrict__ dtg,
    const ushort* __restrict__ xag, const ushort* __restrict__ xdbl,
    const float* __restrict__ A_log, float* __restrict__ Pc, float* __restrict__ Hc) {
  __shared__ float du[128][36];     // (dt, dt*xa) pairs per d, pad to 144B rows
  __shared__ float Bsh[128][16];
  const int tid = threadIdx.x;
  const int c = blockIdx.x, dg = blockIdx.y;
  const int l0 = c * CH;
  {
    int row = tid >> 1, half = tid & 1;
    const size_t gb = (size_t)(l0 + row) * 256 + dg * 16 + half * 8;
    short8v dv = *(const short8v*)&dtg[gb];
    short8v xv = *(const short8v*)&xag[gb];
    float o[16];
    #pragma unroll
    for (int j = 0; j < 8; ++j) {
      float dtf = bf2f((ushort)dv[j]);
      o[j * 2] = dtf; o[j * 2 + 1] = dtf * bf2f((ushort)xv[j]);
    }
    #pragma unroll
    for (int j = 0; j < 4; ++j)
      *(float4*)&du[row][half * 16 + j * 4] =
          make_float4(o[j * 4], o[j * 4 + 1], o[j * 4 + 2], o[j * 4 + 3]);
    if (tid < 128) {
      short8v b0 = *(const short8v*)&xdbl[(size_t)(l0 + tid) * 48 + 8];
      short8v b1 = *(const short8v*)&xdbl[(size_t)(l0 + tid) * 48 + 16];
      #pragma unroll
      for (int j = 0; j < 8; ++j) {
        Bsh[tid][j] = bf2f((ushort)b0[j]);
        Bsh[tid][8 + j] = bf2f((ushort)b1[j]);
      }
    }
  }
  __syncthreads();
  const int s = tid & 15, dloc = tid >> 4;
  const int d = dg * 16 + dloc;
  const float A = -__expf(A_log[d * DS + s]);
  float p = 1.f, h = 0.f;
  #pragma unroll 4
  for (int i = 0; i < CH; ++i) {
    float dtv = du[i][dloc * 2], dx = du[i][dloc * 2 + 1];
    float a = __expf(dtv * A);
    p *= a;
    h = fmaf(a, h, dx * Bsh[i][s]);
  }
  int idx = (c * DI + d) * DS + s;
  Pc[idx] = p; Hc[idx] = h;
}

// ---------------- scan combine: serial over chunks ----------------
__global__ __launch_bounds__(256) void scan_combine(const float* __restrict__ Pc,
    const float* __restrict__ Hc, float* __restrict__ Hin) {
  int t = blockIdx.x * 256 + threadIdx.x;
  float h = 0.f;
  for (int c = 0; c < NC; ++c) {
    Hin[c * 4096 + t] = h;
    h = Pc[c * 4096 + t] * h + Hc[c * 4096 + t];
  }
}

// ---------------- scan pass 2: replay + DPP reduce + gated epilogue -> yg slabs ----------------
__global__ __launch_bounds__(256) void scan_pass2_t(const ushort* __restrict__ dtg,
    const ushort* __restrict__ xag, const ushort* __restrict__ xdbl,
    const ushort* __restrict__ xz, const float* __restrict__ A_log,
    const float* __restrict__ Dp, const float* __restrict__ Hin,
    ushort* __restrict__ yg) {
  __shared__ float du[128][36];
  __shared__ float bc[128][36];
  __shared__ float ylds[128][20];
  const int tid = threadIdx.x;
  const int c = blockIdx.x, dg = blockIdx.y;
  const int l0 = c * CH;
  {
    int row = tid >> 1, half = tid & 1;
    const size_t gb = (size_t)(l0 + row) * 256 + dg * 16 + half * 8;
    short8v dv = *(const short8v*)&dtg[gb];
    short8v xv = *(const short8v*)&xag[gb];
    float o[16];
    #pragma unroll
    for (int j = 0; j < 8; ++j) {
      float dtf = bf2f((ushort)dv[j]);
      o[j * 2] = dtf; o[j * 2 + 1] = dtf * bf2f((ushort)xv[j]);
    }
    #pragma unroll
    for (int j = 0; j < 4; ++j)
      *(float4*)&du[row][half * 16 + j * 4] =
          make_float4(o[j * 4], o[j * 4 + 1], o[j * 4 + 2], o[j * 4 + 3]);
    if (tid < 128) {
      const size_t xb = (size_t)(l0 + tid) * 48;
      short8v b0 = *(const short8v*)&xdbl[xb + 8];
      short8v b1 = *(const short8v*)&xdbl[xb + 16];
      short8v c0 = *(const short8v*)&xdbl[xb + 24];
      short8v c1 = *(const short8v*)&xdbl[xb + 32];
      #pragma unroll
      for (int j = 0; j < 8; ++j) {
        bc[tid][j * 2]           = bf2f((ushort)b0[j]);
        bc[tid][j * 2 + 1]       = bf2f((ushort)c0[j]);
        bc[tid][16 + j * 2]      = bf2f((ushort)b1[j]);
        bc[tid][16 + j * 2 + 1]  = bf2f((ushort)c1[j]);
      }
    }
  }
  __syncthreads();
  const int s = tid & 15, dloc = tid >> 4;
  const int d = dg * 16 + dloc;
  const float A = -__expf(A_log[d * DS + s]);
  float h = Hin[c * 4096 + d * DS + s];
  #pragma unroll 4
  for (int i = 0; i < CH; ++i) {
    float dtv = du[i][dloc * 2], dx = du[i][dloc * 2 + 1];
    float Bv = bc[i][s * 2], Cv = bc[i][s * 2 + 1];
    float a = __expf(dtv * A);
    h = fmaf(a, h, dx * Bv);
    float t = h * Cv;
    t = dpp_add<0xB1>(t);    // xor 1
    t = dpp_add<0x4E>(t);    // xor 2
    t = dpp_add<0x141>(t);   // row_half_mirror
    t = dpp_add<0x140>(t);   // row_mirror -> full 16-lane sum
    if (s == 0) ylds[i][dloc] = t;
  }
  __syncthreads();
  if (tid < 128) {
    int row = tid;
    const size_t gxa = (size_t)(l0 + row) * 256 + dg * 16;
    const size_t gz  = (size_t)(l0 + row) * 512 + 256 + dg * 16;
    short8v xv0 = *(const short8v*)&xag[gxa];
    short8v xv1 = *(const short8v*)&xag[gxa + 8];
    short8v zv0 = *(const short8v*)&xz[gz];
    short8v zv1 = *(const short8v*)&xz[gz + 8];
    ushort o[16];
    #pragma unroll
    for (int j = 0; j < 16; ++j) {
      float yv = ylds[row][j];
      float xf = bf2f((ushort)(j < 8 ? xv0[j] : xv1[j - 8]));
      float zf = bf2f((ushort)(j < 8 ? zv0[j] : zv1[j - 8]));
      float val = (yv + xf * Dp[dg * 16 + j]) * (zf / (1.f + __expf(-zf)));
      o[j] = f2bf(val);
    }
    ushort* dst = &yg[((size_t)dg * LQ + l0 + row) * 16];
    #pragma unroll
    for (int j = 0; j < 8; ++j) {
      ((ushort*)dst)[j] = o[j];
      ((ushort*)dst)[8 + j] = o[8 + j];
    }
  }
}

extern "C" void kernel_launch(void* const* d_in, const int* in_sizes, int n_in,
                              void* d_out, int out_size, void* d_ws, size_t ws_size,
                              hipStream_t stream) {
  const float* x         = (const float*)d_in[0];
  const float* ln_w      = (const float*)d_in[1];
  const float* ln_b      = (const float*)d_in[2];
  const float* in_proj_w = (const float*)d_in[3];
  const float* conv_w    = (const float*)d_in[4];
  const float* conv_b    = (const float*)d_in[5];
  const float* x_proj_w  = (const float*)d_in[6];
  const float* dt_proj_w = (const float*)d_in[7];
  const float* dt_proj_b = (const float*)d_in[8];
  const float* A_log     = (const float*)d_in[9];
  const float* D_param   = (const float*)d_in[10];
  const float* out_proj_w= (const float*)d_in[11];
  float* out = (float*)d_out;

  char* ws = (char*)d_ws;
  ushort* wbf_in  = (ushort*)(ws + 0);           // 512x128
  ushort* wbf_xp  = (ushort*)(ws + 131072);      // 64x256 (padded)
  ushort* wbf_out = (ushort*)(ws + 163840);      // 128x256
  ushort* tn_t    = (ushort*)(ws + 229376);      // (L,128)
  ushort* xz_t    = (ushort*)(ws + 3768320);     // (L,512): xs=0..255, z=256..511
  ushort* xa_t    = (ushort*)(ws + 17924096);    // (L,256)
  ushort* xdbl_t  = (ushort*)(ws + 25001984);    // (L,48): dt_in 0..7, B 8..23, C 24..39
  ushort* dt_t    = (ushort*)(ws + 26329088);    // (L,256)
  ushort* yg_t    = (ushort*)(ws + 33406976);    // 16 slabs (L,16)
  float*  Pc      = (float*)(ws + 40484864);
  float*  Hc      = (float*)(ws + 42254336);
  float*  Hin     = (float*)(ws + 44023808);

  prep_w<<<448, 256, 0, stream>>>(in_proj_w, x_proj_w, out_proj_w, wbf_in, wbf_xp, wbf_out);
  ln_t<<<LQ / 64, 256, 0, stream>>>(x, ln_w, ln_b, tn_t);
  gemm_tok<128, 64, 128, 512><<<dim3(NC, 8), 256, 0, stream>>>(wbf_in, tn_t, xz_t);
  conv_silu_t<<<LQ, 256, 0, stream>>>(xz_t, conv_w, conv_b, xa_t);
  gemm_tok<256, 40, 256, 48><<<dim3(NC, 1), 256, 0, stream>>>(wbf_xp, xa_t, xdbl_t);
  dtproj_t<<<LQ, 256, 0, stream>>>(xdbl_t, dt_proj_w, dt_proj_b, dt_t);
  scan_pass1_t<<<dim3(NC, 16), 256, 0, stream>>>(dt_t, xa_t, xdbl_t, A_log, Pc, Hc);
  scan_combine<<<16, 256, 0, stream>>>(Pc, Hc, Hin);
  scan_pass2_t<<<dim3(NC, 16), 256, 0, stream>>>(dt_t, xa_t, xdbl_t, xz_t, A_log, D_param, Hin, yg_t);
  gemm_out_k<<<NC, 256, 0, stream>>>(wbf_out, yg_t, x, out);
}